// Round 6
// baseline (208.626 us; speedup 1.0000x reference)
//
#include <hip/hip_runtime.h>
#include <cstddef>

// Problem constants
#define BB 64
#define NN 207
#define KK 32
#define CC 8
#define DIN 64
#define DOUT 64
#define TILE 8                // positions per sub-tile
#define PAIR 16               // two sub-tiles per block (pipelined)
#define NP 13                 // ceil(207/16) pair-tiles
#define MPAD 68               // mean row stride (272 B): class rows 4 banks apart

typedef float vfloat4 __attribute__((ext_vector_type(4)));  // native vec for nontemporal store

__device__ __forceinline__ float fast_tanh(float v) {
    float e = __expf(2.0f * v);
    return 1.0f - 2.0f * __builtin_amdgcn_rcpf(e + 1.0f);
}

__device__ __forceinline__ void nt_store4(float* p, float a, float b, float c, float d) {
    vfloat4 r; r.x = a; r.y = b; r.z = c; r.w = d;
    __builtin_nontemporal_store(r, (vfloat4*)p);
}

// 16 FMAs: acc[o0..o0+3] += m(d0..d3) * Wt rows d0..d3
__device__ __forceinline__ void fma16(float4& a, const float4 m,
                                      const float4 w0, const float4 w1,
                                      const float4 w2, const float4 w3) {
    a.x = fmaf(m.x, w0.x, a.x); a.y = fmaf(m.x, w0.y, a.y);
    a.z = fmaf(m.x, w0.z, a.z); a.w = fmaf(m.x, w0.w, a.w);
    a.x = fmaf(m.y, w1.x, a.x); a.y = fmaf(m.y, w1.y, a.y);
    a.z = fmaf(m.y, w1.z, a.z); a.w = fmaf(m.y, w1.w, a.w);
    a.x = fmaf(m.z, w2.x, a.x); a.y = fmaf(m.z, w2.y, a.y);
    a.z = fmaf(m.z, w2.z, a.z); a.w = fmaf(m.z, w2.w, a.w);
    a.x = fmaf(m.w, w3.x, a.x); a.y = fmaf(m.w, w3.y, a.y);
    a.z = fmaf(m.w, w3.z, a.z); a.w = fmaf(m.w, w3.w, a.w);
}

template<bool USE_WT>
__device__ __forceinline__ void load_w4(const float* __restrict__ Wtc,
                                        const float* __restrict__ Wc,
                                        int o0, int dc,
                                        float4& w0, float4& w1, float4& w2, float4& w3) {
    if (USE_WT) {   // Wt[c][d][o]: 256 B contiguous per 16-lane group
        w0 = *(const float4*)(Wtc + (size_t)(dc * 4 + 0) * DOUT);
        w1 = *(const float4*)(Wtc + (size_t)(dc * 4 + 1) * DOUT);
        w2 = *(const float4*)(Wtc + (size_t)(dc * 4 + 2) * DOUT);
        w3 = *(const float4*)(Wtc + (size_t)(dc * 4 + 3) * DOUT);
    } else {        // raw W[c][o][d]: gather + in-register 4x4 transpose
        float4 a0 = *(const float4*)(Wc + (size_t)(o0 + 0) * DIN + dc * 4);
        float4 a1 = *(const float4*)(Wc + (size_t)(o0 + 1) * DIN + dc * 4);
        float4 a2 = *(const float4*)(Wc + (size_t)(o0 + 2) * DIN + dc * 4);
        float4 a3 = *(const float4*)(Wc + (size_t)(o0 + 3) * DIN + dc * 4);
        w0 = make_float4(a0.x, a1.x, a2.x, a3.x);
        w1 = make_float4(a0.y, a1.y, a2.y, a3.y);
        w2 = make_float4(a0.z, a1.z, a2.z, a3.z);
        w3 = make_float4(a0.w, a1.w, a2.w, a3.w);
    }
}

// ---- kernel 0: W[C][DOUT][DIN] -> Wt[C][DIN][DOUT] ----
__global__ __launch_bounds__(256) void transpose_W_kernel(
    const float* __restrict__ W, float* __restrict__ Wt)
{
    __shared__ float t[DIN * (DOUT + 1)];
    const int c   = blockIdx.x;
    const int tid = threadIdx.x;
    const float* __restrict__ Wc  = W  + (size_t)c * DOUT * DIN;
    float* __restrict__       Wtc = Wt + (size_t)c * DIN * DOUT;
    #pragma unroll
    for (int r = 0; r < 16; ++r) {
        const int i = r * 256 + tid;
        const int o = i >> 6, d = i & 63;
        t[d * (DOUT + 1) + o] = Wc[i];
    }
    __syncthreads();
    #pragma unroll
    for (int r = 0; r < 16; ++r) {
        const int i = r * 256 + tid;
        const int d = i >> 6, o = i & 63;
        Wtc[i] = t[d * (DOUT + 1) + o];
    }
}

// ---- main kernel: two 8-pos sub-tiles, phase1(t1) pipelined under phase2(t0) ----
template<bool USE_WT>
__global__ __launch_bounds__(256, 4) void ordered_gcn_kernel(
    const int* __restrict__ idx,      // [B, N, K]
    const float* __restrict__ x,      // [B, N, K, DIN]
    const float* __restrict__ W,      // [C, DOUT, DIN]
    const float* __restrict__ Wt,     // [C, DIN, DOUT]
    float* __restrict__ out)          // [B, N, C, DOUT]
{
    __shared__ int   idx_s[PAIR * KK];           // 2 KB
    __shared__ float inv_s[PAIR * CC];           // 512 B
    __shared__ float meanA[TILE * CC * MPAD];    // 17408 B (tile 0)
    __shared__ float meanB[TILE * CC * MPAD];    // 17408 B (tile 1)

    const int tid = threadIdx.x;
    const int b   = blockIdx.y;
    const int n0  = blockIdx.x * PAIR;

    // ---- idx tile: 512 ints, coalesced ----
    #pragma unroll
    for (int r = 0; r < 2; ++r) {
        const int i = r * 256 + tid;
        const int P = i >> 5, k = i & 31;
        int n = n0 + P; if (n > NN - 1) n = NN - 1;   // clamped rows never stored
        idx_s[i] = idx[((size_t)(b * NN + n)) * KK + k];
    }
    __syncthreads();

    // ---- counts -> inverse clamped counts (128 threads) ----
    if (tid < PAIR * CC) {
        const int P = tid >> 3, c = tid & 7;
        int cnt = 0;
        #pragma unroll
        for (int k = 0; k < KK; ++k) cnt += (idx_s[P * KK + k] == c) ? 1 : 0;
        inv_s[tid] = 1.0f / (float)(cnt > 1 ? cnt : 1);
    }

    // ---- phase-1 thread mapping: (p = tid>>5 in 0..7, d2 = (tid&31)*2) ----
    const int p  = tid >> 5;
    const int d2 = (tid & 31) * 2;
    int na = n0 + p;        if (na > NN - 1) na = NN - 1;
    int nb = n0 + TILE + p; if (nb > NN - 1) nb = NN - 1;
    const float* __restrict__ xp0 = x + ((size_t)(b * NN + na)) * KK * DIN + d2;
    const float* __restrict__ xp1 = x + ((size_t)(b * NN + nb)) * KK * DIN + d2;

    // ---- phase 1, tile 0 (prologue, latency exposed) ----
    float2 acc0[CC];
    #pragma unroll
    for (int c = 0; c < CC; ++c) acc0[c] = make_float2(0.f, 0.f);
    #pragma unroll 1
    for (int g = 0; g < 4; ++g) {
        float2 v[8];
        #pragma unroll
        for (int j = 0; j < 8; ++j)
            v[j] = *(const float2*)(xp0 + (size_t)(g * 8 + j) * DIN);
        #pragma unroll
        for (int j = 0; j < 8; ++j) {
            const int ca = idx_s[p * KK + g * 8 + j];
            #pragma unroll
            for (int c = 0; c < CC; ++c) {
                const float mf = (ca == c) ? 1.0f : 0.0f;
                acc0[c].x = fmaf(mf, v[j].x, acc0[c].x);
                acc0[c].y = fmaf(mf, v[j].y, acc0[c].y);
            }
        }
    }
    __syncthreads();   // inv_s ready
    #pragma unroll
    for (int c = 0; c < CC; ++c) {
        const float s = inv_s[p * CC + c];
        float2 m; m.x = acc0[c].x * s; m.y = acc0[c].y * s;
        *(float2*)(&meanA[(p * CC + c) * MPAD + d2]) = m;
    }
    __syncthreads();   // meanA visible

    // ---- phase-2 thread mapping ----
    const int ph = tid >> 7;            // 0..1 -> pos 4ph..4ph+3
    const int c2 = (tid >> 4) & 7;
    const int o0 = (tid & 15) * 4;
    const float* __restrict__ Wtc = Wt + (size_t)c2 * DIN * DOUT + o0;
    const float* __restrict__ Wc  = W  + (size_t)c2 * DOUT * DIN;

    float4 acc2[4];
    #pragma unroll
    for (int pp = 0; pp < 4; ++pp) acc2[pp] = make_float4(0.f, 0.f, 0.f, 0.f);
    float2 acc1[CC];
    #pragma unroll
    for (int c = 0; c < CC; ++c) acc1[c] = make_float2(0.f, 0.f);

    // ---- fused pipeline: issue t1 loads, run t0 GEMM chunk, consume t1 loads ----
    #pragma unroll 1
    for (int g = 0; g < 4; ++g) {
        float2 v[8];
        #pragma unroll
        for (int j = 0; j < 8; ++j)
            v[j] = *(const float2*)(xp1 + (size_t)(g * 8 + j) * DIN);

        // t0 GEMM chunk: dc = 4g .. 4g+3  (256 FMA hides the load latency)
        #pragma unroll
        for (int dq = 0; dq < 4; ++dq) {
            const int dc = g * 4 + dq;
            float4 w0, w1, w2, w3;
            load_w4<USE_WT>(Wtc, Wc, o0, dc, w0, w1, w2, w3);
            #pragma unroll
            for (int pp = 0; pp < 4; ++pp) {
                const float4 m = *(const float4*)(&meanA[((ph * 4 + pp) * CC + c2) * MPAD + dc * 4]);
                fma16(acc2[pp], m, w0, w1, w2, w3);
            }
        }

        // consume t1 loads
        #pragma unroll
        for (int j = 0; j < 8; ++j) {
            const int ca = idx_s[(TILE + p) * KK + g * 8 + j];
            #pragma unroll
            for (int c = 0; c < CC; ++c) {
                const float mf = (ca == c) ? 1.0f : 0.0f;
                acc1[c].x = fmaf(mf, v[j].x, acc1[c].x);
                acc1[c].y = fmaf(mf, v[j].y, acc1[c].y);
            }
        }
    }

    // ---- write meanB (tile 1) ----
    #pragma unroll
    for (int c = 0; c < CC; ++c) {
        const float s = inv_s[(TILE + p) * CC + c];
        float2 m; m.x = acc1[c].x * s; m.y = acc1[c].y * s;
        *(float2*)(&meanB[(p * CC + c) * MPAD + d2]) = m;
    }
    __syncthreads();   // meanB visible

    // ---- tile 0 epilogue (regs held across barrier; stores after it) ----
    #pragma unroll
    for (int pp = 0; pp < 4; ++pp) {
        const int nn = n0 + ph * 4 + pp;
        if (nn < NN) {
            nt_store4(out + (((size_t)(b * NN + nn)) * CC + c2) * DOUT + o0,
                      fast_tanh(acc2[pp].x), fast_tanh(acc2[pp].y),
                      fast_tanh(acc2[pp].z), fast_tanh(acc2[pp].w));
        }
    }

    // ---- phase 2, tile 1 (tail) ----
    float4 acc3[4];
    #pragma unroll
    for (int pp = 0; pp < 4; ++pp) acc3[pp] = make_float4(0.f, 0.f, 0.f, 0.f);
    #pragma unroll 1
    for (int dc = 0; dc < 16; ++dc) {
        float4 w0, w1, w2, w3;
        load_w4<USE_WT>(Wtc, Wc, o0, dc, w0, w1, w2, w3);
        #pragma unroll
        for (int pp = 0; pp < 4; ++pp) {
            const float4 m = *(const float4*)(&meanB[((ph * 4 + pp) * CC + c2) * MPAD + dc * 4]);
            fma16(acc3[pp], m, w0, w1, w2, w3);
        }
    }
    #pragma unroll
    for (int pp = 0; pp < 4; ++pp) {
        const int nn = n0 + TILE + ph * 4 + pp;
        if (nn < NN) {
            nt_store4(out + (((size_t)(b * NN + nn)) * CC + c2) * DOUT + o0,
                      fast_tanh(acc3[pp].x), fast_tanh(acc3[pp].y),
                      fast_tanh(acc3[pp].z), fast_tanh(acc3[pp].w));
        }
    }
}

extern "C" void kernel_launch(void* const* d_in, const int* in_sizes, int n_in,
                              void* d_out, int out_size, void* d_ws, size_t ws_size,
                              hipStream_t stream) {
    const int*   idx = (const int*)d_in[0];    // [B,N,K] int32
    const float* x   = (const float*)d_in[1];  // [B,N,K,DIN] f32
    const float* W   = (const float*)d_in[2];  // [C,DOUT,DIN] f32
    float* out = (float*)d_out;                // [B,N,C,DOUT] f32
    float* Wt  = (float*)d_ws;                 // [C,DIN,DOUT] scratch (128 KB)

    dim3 grid(NP, BB);   // 13 x 64 = 832 blocks, 2 sub-tiles each
    dim3 block(256);
    const size_t wt_bytes = (size_t)CC * DIN * DOUT * sizeof(float);
    if (ws_size >= wt_bytes) {
        transpose_W_kernel<<<dim3(CC), block, 0, stream>>>(W, Wt);
        ordered_gcn_kernel<true><<<grid, block, 0, stream>>>(idx, x, W, Wt, out);
    } else {
        ordered_gcn_kernel<false><<<grid, block, 0, stream>>>(idx, x, W, Wt, out);
    }
}

// Round 7
// 205.381 us; speedup vs baseline: 1.0158x; 1.0158x over previous
//
#include <hip/hip_runtime.h>
#include <cstddef>

// Problem constants
#define BB 64
#define NN 207
#define KK 32
#define CC 8
#define DIN 64
#define DOUT 64
#define TILE 16               // n-positions per block
#define NT 13                 // ceil(207/16)
#define MPADH 68              // mean row stride in bf16 halfwords (136 B): rows 2 banks apart

__device__ __forceinline__ float fast_tanh(float v) {
    float e = __expf(2.0f * v);
    return 1.0f - 2.0f * __builtin_amdgcn_rcpf(e + 1.0f);
}

// fp32 -> bf16 bits, round-to-nearest-even
__device__ __forceinline__ unsigned int f2bf(float f) {
    union { float f; unsigned int u; } v; v.f = f;
    return (v.u + 0x7fffu + ((v.u >> 16) & 1u)) >> 16;
}

// 16 FMAs: acc[o0..o0+3] += m(d0..d3) * Wt rows d0..d3
__device__ __forceinline__ void fma16(float4& a, const float4 m,
                                      const float4 w0, const float4 w1,
                                      const float4 w2, const float4 w3) {
    a.x = fmaf(m.x, w0.x, a.x); a.y = fmaf(m.x, w0.y, a.y);
    a.z = fmaf(m.x, w0.z, a.z); a.w = fmaf(m.x, w0.w, a.w);
    a.x = fmaf(m.y, w1.x, a.x); a.y = fmaf(m.y, w1.y, a.y);
    a.z = fmaf(m.y, w1.z, a.z); a.w = fmaf(m.y, w1.w, a.w);
    a.x = fmaf(m.z, w2.x, a.x); a.y = fmaf(m.z, w2.y, a.y);
    a.z = fmaf(m.z, w2.z, a.z); a.w = fmaf(m.z, w2.w, a.w);
    a.x = fmaf(m.w, w3.x, a.x); a.y = fmaf(m.w, w3.y, a.y);
    a.z = fmaf(m.w, w3.z, a.z); a.w = fmaf(m.w, w3.w, a.w);
}

template<bool USE_WT>
__device__ __forceinline__ void load_w4(const float* __restrict__ Wtc,
                                        const float* __restrict__ Wc,
                                        int o0, int dc,
                                        float4& w0, float4& w1, float4& w2, float4& w3) {
    if (USE_WT) {   // Wt[c][d][o]: 256 B contiguous per 16-lane group
        w0 = *(const float4*)(Wtc + (size_t)(dc * 4 + 0) * DOUT);
        w1 = *(const float4*)(Wtc + (size_t)(dc * 4 + 1) * DOUT);
        w2 = *(const float4*)(Wtc + (size_t)(dc * 4 + 2) * DOUT);
        w3 = *(const float4*)(Wtc + (size_t)(dc * 4 + 3) * DOUT);
    } else {        // raw W[c][o][d]: gather + in-register 4x4 transpose
        float4 a0 = *(const float4*)(Wc + (size_t)(o0 + 0) * DIN + dc * 4);
        float4 a1 = *(const float4*)(Wc + (size_t)(o0 + 1) * DIN + dc * 4);
        float4 a2 = *(const float4*)(Wc + (size_t)(o0 + 2) * DIN + dc * 4);
        float4 a3 = *(const float4*)(Wc + (size_t)(o0 + 3) * DIN + dc * 4);
        w0 = make_float4(a0.x, a1.x, a2.x, a3.x);
        w1 = make_float4(a0.y, a1.y, a2.y, a3.y);
        w2 = make_float4(a0.z, a1.z, a2.z, a3.z);
        w3 = make_float4(a0.w, a1.w, a2.w, a3.w);
    }
}

// ---- kernel 0: W[C][DOUT][DIN] -> Wt[C][DIN][DOUT] ----
__global__ __launch_bounds__(256) void transpose_W_kernel(
    const float* __restrict__ W, float* __restrict__ Wt)
{
    __shared__ float t[DIN * (DOUT + 1)];
    const int c   = blockIdx.x;
    const int tid = threadIdx.x;
    const float* __restrict__ Wc  = W  + (size_t)c * DOUT * DIN;
    float* __restrict__       Wtc = Wt + (size_t)c * DIN * DOUT;
    #pragma unroll
    for (int r = 0; r < 16; ++r) {
        const int i = r * 256 + tid;
        const int o = i >> 6, d = i & 63;
        t[d * (DOUT + 1) + o] = Wc[i];
    }
    __syncthreads();
    #pragma unroll
    for (int r = 0; r < 16; ++r) {
        const int i = r * 256 + tid;
        const int d = i >> 6, o = i & 63;
        Wtc[i] = t[d * (DOUT + 1) + o];
    }
}

// ---- main kernel: R4 structure, mean staged in LDS as bf16 ----
template<bool USE_WT>
__global__ __launch_bounds__(256, 6) void ordered_gcn_kernel(
    const int* __restrict__ idx,      // [B, N, K]
    const float* __restrict__ x,      // [B, N, K, DIN]
    const float* __restrict__ W,      // [C, DOUT, DIN]
    const float* __restrict__ Wt,     // [C, DIN, DOUT]
    float* __restrict__ out)          // [B, N, C, DOUT]
{
    __shared__ int            idx_s[TILE * KK];           // 2048 B
    __shared__ float          inv_s[TILE * CC];           // 512 B
    __shared__ unsigned short mean_s[TILE * CC * MPADH];  // 17408 B  (total 19968 B)

    const int tid = threadIdx.x;
    const int b   = blockIdx.y;
    const int n0  = blockIdx.x * TILE;

    // ---- idx tile: 512 ints, coalesced ----
    #pragma unroll
    for (int r = 0; r < 2; ++r) {
        const int i = r * 256 + tid;
        const int P = i >> 5, k = i & 31;
        int n = n0 + P; if (n > NN - 1) n = NN - 1;   // clamped rows never stored
        idx_s[i] = idx[((size_t)(b * NN + n)) * KK + k];
    }
    __syncthreads();

    // ---- counts -> inverse clamped counts (128 threads) ----
    if (tid < TILE * CC) {
        const int P = tid >> 3, c = tid & 7;
        int cnt = 0;
        #pragma unroll
        for (int k = 0; k < KK; ++k) cnt += (idx_s[P * KK + k] == c) ? 1 : 0;
        inv_s[tid] = 1.0f / (float)(cnt > 1 ? cnt : 1);
    }

    // ---- phase 1: class-bucketed float4 sums, 8-deep load batches ----
    // thread = (p = tid>>4 in 0..15, d4 = (tid&15)*4); 16 float4 loads/thread.
    {
        const int p  = tid >> 4;
        const int d4 = (tid & 15) * 4;
        int n = n0 + p; if (n > NN - 1) n = NN - 1;
        const float* __restrict__ xp = x + ((size_t)(b * NN + n)) * KK * DIN + d4;

        float4 acc[CC];
        #pragma unroll
        for (int c = 0; c < CC; ++c) acc[c] = make_float4(0.f, 0.f, 0.f, 0.f);

        #pragma unroll 1   // keep batches sequential: 8 loads in flight
        for (int g = 0; g < 2; ++g) {
            float4 v[8];
            #pragma unroll
            for (int j = 0; j < 8; ++j)
                v[j] = *(const float4*)(xp + (size_t)(g * 8 + j) * DIN);
            #pragma unroll
            for (int j = 0; j < 8; ++j) {
                const int ca = idx_s[p * KK + g * 8 + j];
                #pragma unroll
                for (int c = 0; c < CC; ++c) {
                    const float mf = (ca == c) ? 1.0f : 0.0f;
                    acc[c].x = fmaf(mf, v[j].x, acc[c].x);
                    acc[c].y = fmaf(mf, v[j].y, acc[c].y);
                    acc[c].z = fmaf(mf, v[j].z, acc[c].z);
                    acc[c].w = fmaf(mf, v[j].w, acc[c].w);
                }
            }
        }
        // second half of K
        #pragma unroll 1
        for (int g = 2; g < 4; ++g) {
            float4 v[8];
            #pragma unroll
            for (int j = 0; j < 8; ++j)
                v[j] = *(const float4*)(xp + (size_t)(g * 8 + j) * DIN);
            #pragma unroll
            for (int j = 0; j < 8; ++j) {
                const int ca = idx_s[p * KK + g * 8 + j];
                #pragma unroll
                for (int c = 0; c < CC; ++c) {
                    const float mf = (ca == c) ? 1.0f : 0.0f;
                    acc[c].x = fmaf(mf, v[j].x, acc[c].x);
                    acc[c].y = fmaf(mf, v[j].y, acc[c].y);
                    acc[c].z = fmaf(mf, v[j].z, acc[c].z);
                    acc[c].w = fmaf(mf, v[j].w, acc[c].w);
                }
            }
        }
        __syncthreads();   // inv_s ready

        #pragma unroll
        for (int c = 0; c < CC; ++c) {
            const float s = inv_s[p * CC + c];
            const unsigned int lo = f2bf(acc[c].x * s) | (f2bf(acc[c].y * s) << 16);
            const unsigned int hi = f2bf(acc[c].z * s) | (f2bf(acc[c].w * s) << 16);
            *(uint2*)(&mean_s[(p * CC + c) * MPADH + d4]) = make_uint2(lo, hi);
        }
    }
    __syncthreads();   // mean_s visible

    // ---- phase 2: out[p][c][o] = tanh(sum_d mean[p][c][d] * Wt[c][d][o]) ----
    // thread = (ph = tid>>7 -> pos 8ph..8ph+7, c2 = (tid>>4)&7, o0 = (tid&15)*4)
    {
        const int ph = tid >> 7;
        const int c2 = (tid >> 4) & 7;
        const int o0 = (tid & 15) * 4;
        const float* __restrict__ Wtc = Wt + (size_t)c2 * DIN * DOUT + o0;
        const float* __restrict__ Wc  = W  + (size_t)c2 * DOUT * DIN;

        float4 acc2[8];
        #pragma unroll
        for (int pp = 0; pp < 8; ++pp) acc2[pp] = make_float4(0.f, 0.f, 0.f, 0.f);

        #pragma unroll 2
        for (int dc = 0; dc < 16; ++dc) {
            float4 w0, w1, w2, w3;
            load_w4<USE_WT>(Wtc, Wc, o0, dc, w0, w1, w2, w3);
            #pragma unroll
            for (int pp = 0; pp < 8; ++pp) {
                const uint2 mw = *(const uint2*)(&mean_s[((ph * 8 + pp) * CC + c2) * MPADH + dc * 4]);
                float4 m;
                m.x = __uint_as_float(mw.x << 16);
                m.y = __uint_as_float(mw.x & 0xffff0000u);
                m.z = __uint_as_float(mw.y << 16);
                m.w = __uint_as_float(mw.y & 0xffff0000u);
                fma16(acc2[pp], m, w0, w1, w2, w3);
            }
        }

        #pragma unroll
        for (int pp = 0; pp < 8; ++pp) {
            const int nn = n0 + ph * 8 + pp;
            if (nn < NN) {
                float4 r;
                r.x = fast_tanh(acc2[pp].x);
                r.y = fast_tanh(acc2[pp].y);
                r.z = fast_tanh(acc2[pp].z);
                r.w = fast_tanh(acc2[pp].w);
                *(float4*)(out + (((size_t)(b * NN + nn)) * CC + c2) * DOUT + o0) = r;
            }
        }
    }
}

extern "C" void kernel_launch(void* const* d_in, const int* in_sizes, int n_in,
                              void* d_out, int out_size, void* d_ws, size_t ws_size,
                              hipStream_t stream) {
    const int*   idx = (const int*)d_in[0];    // [B,N,K] int32
    const float* x   = (const float*)d_in[1];  // [B,N,K,DIN] f32
    const float* W   = (const float*)d_in[2];  // [C,DOUT,DIN] f32
    float* out = (float*)d_out;                // [B,N,C,DOUT] f32
    float* Wt  = (float*)d_ws;                 // [C,DIN,DOUT] scratch (128 KB)

    dim3 grid(NT, BB);   // 13 x 64 = 832 blocks
    dim3 block(256);
    const size_t wt_bytes = (size_t)CC * DIN * DOUT * sizeof(float);
    if (ws_size >= wt_bytes) {
        transpose_W_kernel<<<dim3(CC), block, 0, stream>>>(W, Wt);
        ordered_gcn_kernel<true><<<grid, block, 0, stream>>>(idx, x, W, Wt, out);
    } else {
        ordered_gcn_kernel<false><<<grid, block, 0, stream>>>(idx, x, W, Wt, out);
    }
}

// Round 8
// 188.428 us; speedup vs baseline: 1.1072x; 1.0900x over previous
//
#include <hip/hip_runtime.h>
#include <cstddef>

// Problem constants
#define BB 64
#define NN 207
#define KK 32
#define CC 8
#define DIN 64
#define DOUT 64
#define TILE 4                // n-positions per block
#define NT 52                 // ceil(207/4)
#define MPAD 68               // mean row stride: phase-2 pos-rows on distinct banks

__device__ __forceinline__ float fast_tanh(float v) {
    float e = __expf(2.0f * v);
    return 1.0f - 2.0f * __builtin_amdgcn_rcpf(e + 1.0f);
}

// 16 FMAs: acc[o0..o0+3] += m(d0..d3) * Wt rows d0..d3
__device__ __forceinline__ void fma16(float4& a, const float4 m,
                                      const float4 w0, const float4 w1,
                                      const float4 w2, const float4 w3) {
    a.x = fmaf(m.x, w0.x, a.x); a.y = fmaf(m.x, w0.y, a.y);
    a.z = fmaf(m.x, w0.z, a.z); a.w = fmaf(m.x, w0.w, a.w);
    a.x = fmaf(m.y, w1.x, a.x); a.y = fmaf(m.y, w1.y, a.y);
    a.z = fmaf(m.y, w1.z, a.z); a.w = fmaf(m.y, w1.w, a.w);
    a.x = fmaf(m.z, w2.x, a.x); a.y = fmaf(m.z, w2.y, a.y);
    a.z = fmaf(m.z, w2.z, a.z); a.w = fmaf(m.z, w2.w, a.w);
    a.x = fmaf(m.w, w3.x, a.x); a.y = fmaf(m.w, w3.y, a.y);
    a.z = fmaf(m.w, w3.z, a.z); a.w = fmaf(m.w, w3.w, a.w);
}

template<bool USE_WT>
__device__ __forceinline__ void load_w4(const float* __restrict__ Wtc,
                                        const float* __restrict__ Wc,
                                        int o0, int dc,
                                        float4& w0, float4& w1, float4& w2, float4& w3) {
    if (USE_WT) {   // Wt[c][d][o]: contiguous per 16-lane group
        w0 = *(const float4*)(Wtc + (size_t)(dc * 4 + 0) * DOUT);
        w1 = *(const float4*)(Wtc + (size_t)(dc * 4 + 1) * DOUT);
        w2 = *(const float4*)(Wtc + (size_t)(dc * 4 + 2) * DOUT);
        w3 = *(const float4*)(Wtc + (size_t)(dc * 4 + 3) * DOUT);
    } else {        // raw W[c][o][d]: gather + in-register 4x4 transpose
        float4 a0 = *(const float4*)(Wc + (size_t)(o0 + 0) * DIN + dc * 4);
        float4 a1 = *(const float4*)(Wc + (size_t)(o0 + 1) * DIN + dc * 4);
        float4 a2 = *(const float4*)(Wc + (size_t)(o0 + 2) * DIN + dc * 4);
        float4 a3 = *(const float4*)(Wc + (size_t)(o0 + 3) * DIN + dc * 4);
        w0 = make_float4(a0.x, a1.x, a2.x, a3.x);
        w1 = make_float4(a0.y, a1.y, a2.y, a3.y);
        w2 = make_float4(a0.z, a1.z, a2.z, a3.z);
        w3 = make_float4(a0.w, a1.w, a2.w, a3.w);
    }
}

// ---- kernel 0: W[C][DOUT][DIN] -> Wt[C][DIN][DOUT] ----
__global__ __launch_bounds__(256) void transpose_W_kernel(
    const float* __restrict__ W, float* __restrict__ Wt)
{
    __shared__ float t[DIN * (DOUT + 1)];
    const int c   = blockIdx.x;
    const int tid = threadIdx.x;
    const float* __restrict__ Wc  = W  + (size_t)c * DOUT * DIN;
    float* __restrict__       Wtc = Wt + (size_t)c * DIN * DOUT;
    #pragma unroll
    for (int r = 0; r < 16; ++r) {
        const int i = r * 256 + tid;
        const int o = i >> 6, d = i & 63;
        t[d * (DOUT + 1) + o] = Wc[i];
    }
    __syncthreads();
    #pragma unroll
    for (int r = 0; r < 16; ++r) {
        const int i = r * 256 + tid;
        const int d = i >> 6, o = i & 63;
        Wtc[i] = t[d * (DOUT + 1) + o];
    }
}

// ---- main kernel: TILE=4, one pos per wave, K 4-way split + shfl reduce ----
template<bool USE_WT>
__global__ __launch_bounds__(256, 4) void ordered_gcn_kernel(
    const int* __restrict__ idx,      // [B, N, K]
    const float* __restrict__ x,      // [B, N, K, DIN]
    const float* __restrict__ W,      // [C, DOUT, DIN]
    const float* __restrict__ Wt,     // [C, DIN, DOUT]
    float* __restrict__ out)          // [B, N, C, DOUT]
{
    __shared__ int   idx_s[TILE * KK];          // 512 B
    __shared__ float inv_s[TILE * CC];          // 128 B
    __shared__ float mean_s[TILE * CC * MPAD];  // 8704 B   (total ~9.4 KB)

    const int tid = threadIdx.x;
    const int b   = blockIdx.y;
    const int n0  = blockIdx.x * TILE;

    // ---- idx tile: 128 ints, coalesced ----
    if (tid < TILE * KK) {
        const int P = tid >> 5, k = tid & 31;
        int n = n0 + P; if (n > NN - 1) n = NN - 1;   // clamped rows never stored
        idx_s[tid] = idx[((size_t)(b * NN + n)) * KK + k];
    }
    __syncthreads();

    // ---- counts -> inverse clamped counts (32 threads) ----
    if (tid < TILE * CC) {
        const int P = tid >> 3, c = tid & 7;
        int cnt = 0;
        #pragma unroll
        for (int k = 0; k < KK; ++k) cnt += (idx_s[P * KK + k] == c) ? 1 : 0;
        inv_s[tid] = 1.0f / (float)(cnt > 1 ? cnt : 1);
    }
    // (inv_s consumed after the barrier below)

    // ---- phase 1: one pos per wave; lane = (kq = ln>>4, d4 = (ln&15)*4) ----
    // Each thread: its ENTIRE load share (8 float4) issued as one batch.
    // Wave address pattern per inst: 4 disjoint contiguous 256 B segments = 1 KB.
    {
        const int p  = tid >> 6;          // 0..3 (one pos per wave)
        const int ln = tid & 63;
        const int kq = ln >> 4;           // k-quarter 0..3
        const int d4 = (ln & 15) * 4;
        int n = n0 + p; if (n > NN - 1) n = NN - 1;
        const float* __restrict__ xp =
            x + (((size_t)(b * NN + n)) * KK + kq * 8) * DIN + d4;

        float4 v[8];
        #pragma unroll
        for (int j = 0; j < 8; ++j)
            v[j] = *(const float4*)(xp + (size_t)j * DIN);

        float4 acc[CC];
        #pragma unroll
        for (int c = 0; c < CC; ++c) acc[c] = make_float4(0.f, 0.f, 0.f, 0.f);

        #pragma unroll
        for (int j = 0; j < 8; ++j) {
            const int ca = idx_s[p * KK + kq * 8 + j];
            #pragma unroll
            for (int c = 0; c < CC; ++c) {
                const float mf = (ca == c) ? 1.0f : 0.0f;
                acc[c].x = fmaf(mf, v[j].x, acc[c].x);
                acc[c].y = fmaf(mf, v[j].y, acc[c].y);
                acc[c].z = fmaf(mf, v[j].z, acc[c].z);
                acc[c].w = fmaf(mf, v[j].w, acc[c].w);
            }
        }

        // butterfly reduce across the 4 k-quarters (lanes xor 16, xor 32)
        #pragma unroll
        for (int c = 0; c < CC; ++c) {
            float* a = (float*)&acc[c];
            #pragma unroll
            for (int q = 0; q < 4; ++q) {
                a[q] += __shfl_xor(a[q], 16, 64);
                a[q] += __shfl_xor(a[q], 32, 64);
            }
        }

        __syncthreads();   // counts (inv_s) visible
        if (kq == 0) {
            #pragma unroll
            for (int c = 0; c < CC; ++c) {
                const float s = inv_s[p * CC + c];
                float4 m;
                m.x = acc[c].x * s; m.y = acc[c].y * s;
                m.z = acc[c].z * s; m.w = acc[c].w * s;
                *(float4*)(&mean_s[(p * CC + c) * MPAD + d4]) = m;
            }
        }
    }
    __syncthreads();   // mean_s visible

    // ---- phase 2: out[p][c][o] = tanh(sum_d mean[p][c][d] * Wt[c][d][o]) ----
    // thread = (c2 = tid>>5, ph = (tid>>4)&1 -> pos pair, o0 = (tid&15)*4)
    {
        const int c2 = tid >> 5;
        const int l2 = tid & 31;
        const int ph = l2 >> 4;           // 0 -> pos {0,1}, 1 -> pos {2,3}
        const int o0 = (l2 & 15) * 4;
        const int p0 = ph * 2, p1 = ph * 2 + 1;

        const float* __restrict__ Wtc = Wt + (size_t)c2 * DIN * DOUT + o0;
        const float* __restrict__ Wc  = W  + (size_t)c2 * DOUT * DIN;

        float4 a0 = make_float4(0.f, 0.f, 0.f, 0.f);
        float4 a1 = make_float4(0.f, 0.f, 0.f, 0.f);

        #pragma unroll 2
        for (int dc = 0; dc < 16; ++dc) {
            float4 w0, w1, w2, w3;
            load_w4<USE_WT>(Wtc, Wc, o0, dc, w0, w1, w2, w3);
            const float4 m0 = *(const float4*)(&mean_s[(p0 * CC + c2) * MPAD + dc * 4]);
            const float4 m1 = *(const float4*)(&mean_s[(p1 * CC + c2) * MPAD + dc * 4]);
            fma16(a0, m0, w0, w1, w2, w3);
            fma16(a1, m1, w0, w1, w2, w3);
        }

        const int nn0 = n0 + p0;
        if (nn0 < NN) {
            float4 r;
            r.x = fast_tanh(a0.x); r.y = fast_tanh(a0.y);
            r.z = fast_tanh(a0.z); r.w = fast_tanh(a0.w);
            *(float4*)(out + (((size_t)(b * NN + nn0)) * CC + c2) * DOUT + o0) = r;
        }
        const int nn1 = n0 + p1;
        if (nn1 < NN) {
            float4 r;
            r.x = fast_tanh(a1.x); r.y = fast_tanh(a1.y);
            r.z = fast_tanh(a1.z); r.w = fast_tanh(a1.w);
            *(float4*)(out + (((size_t)(b * NN + nn1)) * CC + c2) * DOUT + o0) = r;
        }
    }
}

extern "C" void kernel_launch(void* const* d_in, const int* in_sizes, int n_in,
                              void* d_out, int out_size, void* d_ws, size_t ws_size,
                              hipStream_t stream) {
    const int*   idx = (const int*)d_in[0];    // [B,N,K] int32
    const float* x   = (const float*)d_in[1];  // [B,N,K,DIN] f32
    const float* W   = (const float*)d_in[2];  // [C,DOUT,DIN] f32
    float* out = (float*)d_out;                // [B,N,C,DOUT] f32
    float* Wt  = (float*)d_ws;                 // [C,DIN,DOUT] scratch (128 KB)

    dim3 grid(NT, BB);   // 52 x 64 = 3328 blocks
    dim3 block(256);
    const size_t wt_bytes = (size_t)CC * DIN * DOUT * sizeof(float);
    if (ws_size >= wt_bytes) {
        transpose_W_kernel<<<dim3(CC), block, 0, stream>>>(W, Wt);
        ordered_gcn_kernel<true><<<grid, block, 0, stream>>>(idx, x, W, Wt, out);
    } else {
        ordered_gcn_kernel<false><<<grid, block, 0, stream>>>(idx, x, W, Wt, out);
    }
}